// Round 10
// baseline (97.511 us; speedup 1.0000x reference)
//
#include <hip/hip_runtime.h>

// FeaStConv x2, HEADS=1 => softmax==1 => layer = relu((segsum(h[src])@W)/deg + b).
// dur_us model: own kernels + ~40us harness d_ws poison fill (immovable).
// 5 dispatches:
//   k_prep   : zero cnt+ovf_cnt, repack W1 -> packHi/packLo (bf16 MFMA B-frags)
//   k_fill   : per-dst bucket build, CAP-15 (slot 15 reserved; overflow list)
//   k_gather : wave per (node, channel-half); half chosen by blockIdx parity so
//              each XCD's L2 only sees a 3.2MB slice of x (fits 4MiB L2, no thrash).
//              lane = (slot s, quarter q): 1 bucket dword + 1 float4 row read.
//   k_dense  : grid-stride; packs bulk-copied to LDS; 3-term bf16-split MFMA
//              (xs@W1) + relu/deg/b1 + W2 epilogue -> p[N,4]
//   k_out    : wave per node slot-parallel layer-2 gather + bias/relu -> out

#define TPB 256
#define DGRID 512

typedef __attribute__((ext_vector_type(8))) short bf16x8;
typedef __attribute__((ext_vector_type(4))) float f32x4;

__device__ __forceinline__ void split_bf16(float f, ushort& hi, ushort& lo) {
    unsigned u = __float_as_uint(f);
    unsigned h = u >> 16;
    float fh = __uint_as_float(h << 16);
    float r = f - fh;                      // exact
    hi = (ushort)h;
    lo = (ushort)(__float_as_uint(r) >> 16);
}

// blocks [0, zb): zero cnt+ovf_cnt. blocks [zb, zb+7): W1 fragment repack.
__global__ void k_prep(int* __restrict__ cnt, int n1, int zb,
                       const float* __restrict__ W1,
                       ushort* __restrict__ packHi, ushort* __restrict__ packLo) {
    if ((int)blockIdx.x < zb) {
        int gid = blockIdx.x * TPB + threadIdx.x;
        if (gid < n1) cnt[gid] = 0;
    } else {
        int t = (blockIdx.x - zb) * TPB + threadIdx.x;   // 25*64 = 1600 frags
        if (t >= 25 * 64) return;
        int ct = t >> 6, l = t & 63;
        int kh = l >> 4, c = l & 15;
#pragma unroll
        for (int e = 0; e < 8; e++) {
            // B[k][col] fragment: k = 8*kh + e, col = ct*16 + c
            float f = W1[(8 * kh + e) * 400 + ct * 16 + c];
            ushort h, lo; split_bf16(f, h, lo);
            packHi[t * 8 + e] = h;
            packLo[t * 8 + e] = lo;
        }
    }
}

// CAP-15: slots 0..14 in bucket (stride 16), slot>=15 -> overflow list.
__global__ void k_fill(const int* __restrict__ src, const int* __restrict__ dst,
                       int* __restrict__ cnt, int* __restrict__ bucket,
                       int* __restrict__ ovf_cnt, int2* __restrict__ ovf_list, int E) {
    int e = blockIdx.x * TPB + threadIdx.x;
    if (e >= E) return;
    int d = dst[e];
    int s = src[e];
    int slot = atomicAdd(&cnt[d], 1);
    if (slot < 15) bucket[(size_t)d * 16 + slot] = s;
    else { int pos = atomicAdd(ovf_cnt, 1); ovf_list[pos] = make_int2(s, d); }
}

// Wave per (node, half). half = blockIdx&1 -> even XCDs serve channels 0..15,
// odd XCDs channels 16..31 (per-XCD L2 working set 3.2MB, fits).
// Lane l: slot s = l>>2 (0..15), quarter q = l&3 (4 channels).
__global__ __launch_bounds__(256) void k_gather(
    const float* __restrict__ x, const int* __restrict__ cnt,
    const int* __restrict__ bucket, const int* __restrict__ ovf_cnt,
    const int2* __restrict__ ovf_list,
    float* __restrict__ xs, float* __restrict__ invd, int n) {
    int half = blockIdx.x & 1;
    int node = (blockIdx.x >> 1) * 4 + (threadIdx.x >> 6);
    if (node >= n) return;
    int l = threadIdx.x & 63;
    int s = l >> 2, q = l & 3;
    int m = cnt[node];
    int mb = m < 15 ? m : 15;

    int bkt = bucket[(size_t)node * 16 + s];
    int id = (s < mb) ? bkt : node;          // s==mb lane adds the self-loop row
    bool inc = (s <= mb);
    float4 v = *(const float4*)(x + (size_t)id * 32 + half * 16 + q * 4);
    float a0 = inc ? v.x : 0.f, a1 = inc ? v.y : 0.f;
    float a2 = inc ? v.z : 0.f, a3 = inc ? v.w : 0.f;

    if (m > 15) {                            // wave-uniform, rare
        int L = ovf_cnt[0];
        for (int j = s; j < L; j += 16) {
            int2 sd = ovf_list[j];
            if (sd.y == node) {
                float4 w = *(const float4*)(x + (size_t)sd.x * 32 + half * 16 + q * 4);
                a0 += w.x; a1 += w.y; a2 += w.z; a3 += w.w;
            }
        }
    }
#pragma unroll
    for (int mask = 4; mask <= 32; mask <<= 1) {
        a0 += __shfl_xor(a0, mask, 64);
        a1 += __shfl_xor(a1, mask, 64);
        a2 += __shfl_xor(a2, mask, 64);
        a3 += __shfl_xor(a3, mask, 64);
    }
    if (s == 0) {
        *(float4*)(xs + (size_t)node * 32 + half * 16 + q * 4) =
            make_float4(a0, a1, a2, a3);
        if (q == 0 && half == 0)
            invd[node] = __builtin_amdgcn_rcpf((float)(m + 1));
    }
}

// Grid-stride MFMA dense. 4 waves/block, wave-tile = 16 nodes.
// Pack bulk-copied (contiguous uint4) into LDS once per block.
__global__ __launch_bounds__(256) void k_dense(
    const float* __restrict__ xs, const float* __restrict__ invd,
    const ushort* __restrict__ packHi, const ushort* __restrict__ packLo,
    const float* __restrict__ b1, const float* __restrict__ W2,
    float* __restrict__ p, int n) {
    __shared__ __align__(16) ushort sHi[12800];   // 25.6 KB
    __shared__ __align__(16) ushort sLo[12800];   // 25.6 KB
    __shared__ __align__(16) float sW2[1600];     // 6.4 KB
    __shared__ float sb1[400];                    // 1.6 KB
    {
        const uint4* gh = (const uint4*)packHi;
        const uint4* gl = (const uint4*)packLo;
        uint4* sh = (uint4*)sHi;
        uint4* sl = (uint4*)sLo;
        for (int i = threadIdx.x; i < 1600; i += TPB) { sh[i] = gh[i]; sl[i] = gl[i]; }
        for (int i = threadIdx.x; i < 1600; i += TPB) sW2[i] = W2[i];
        for (int i = threadIdx.x; i < 400; i += TPB) sb1[i] = b1[i];
    }
    __syncthreads();

    int wid = threadIdx.x >> 6, l = threadIdx.x & 63;
    int r = l & 15, kh = l >> 4;
    int ntile = (n + 15) >> 4;

    for (int tile = blockIdx.x * 4 + wid; tile < ntile; tile += DGRID * 4) {
        int base = tile * 16;
        int node = base + r; if (node > n - 1) node = n - 1;

        const float4* xp = (const float4*)(xs + (size_t)node * 32 + kh * 8);
        float4 v0 = xp[0], v1 = xp[1];
        float xv[8] = {v0.x, v0.y, v0.z, v0.w, v1.x, v1.y, v1.z, v1.w};
        bf16x8 a_hi, a_lo;
#pragma unroll
        for (int e = 0; e < 8; e++) {
            ushort hi, lo; split_bf16(xv[e], hi, lo);
            a_hi[e] = (short)hi; a_lo[e] = (short)lo;
        }
        float iv = invd[node];                       // lane r holds invd[base+r]
        float invd_q[4];
#pragma unroll
        for (int q = 0; q < 4; q++)
            invd_q[q] = __shfl(iv, (l & 48) + kh * 4 + q, 64);

        float pacc[4][4];
#pragma unroll
        for (int q = 0; q < 4; q++)
#pragma unroll
            for (int o = 0; o < 4; o++) pacc[q][o] = 0.f;

#pragma unroll 5
        for (int ct = 0; ct < 25; ct++) {
            bf16x8 bh = *(const bf16x8*)(sHi + ((ct * 64 + l) << 3));
            bf16x8 bl = *(const bf16x8*)(sLo + ((ct * 64 + l) << 3));
            f32x4 c = {0.f, 0.f, 0.f, 0.f};
            c = __builtin_amdgcn_mfma_f32_16x16x32_bf16(a_hi, bh, c, 0, 0, 0);
            c = __builtin_amdgcn_mfma_f32_16x16x32_bf16(a_lo, bh, c, 0, 0, 0);
            c = __builtin_amdgcn_mfma_f32_16x16x32_bf16(a_hi, bl, c, 0, 0, 0);
            float b1v = sb1[ct * 16 + r];
            const float4 w2v = *(const float4*)(&sW2[(ct * 16 + r) * 4]);
#pragma unroll
            for (int q = 0; q < 4; q++) {
                float hq = fmaxf(fmaf(c[q], invd_q[q], b1v), 0.f);
                pacc[q][0] = fmaf(hq, w2v.x, pacc[q][0]);
                pacc[q][1] = fmaf(hq, w2v.y, pacc[q][1]);
                pacc[q][2] = fmaf(hq, w2v.z, pacc[q][2]);
                pacc[q][3] = fmaf(hq, w2v.w, pacc[q][3]);
            }
        }
        // reduce over r (lane bits 0..3)
#pragma unroll
        for (int mask = 1; mask <= 8; mask <<= 1)
#pragma unroll
            for (int q = 0; q < 4; q++)
#pragma unroll
                for (int o = 0; o < 4; o++)
                    pacc[q][o] += __shfl_xor(pacc[q][o], mask, 64);

        if (r < 4) {
            int nd = base + kh * 4 + r;
            if (nd < n)
                *(float4*)(p + (size_t)nd * 4) =
                    make_float4(pacc[r][0], pacc[r][1], pacc[r][2], pacc[r][3]);
        }
    }
}

// Wave per node. Lane l: slot s = l>>2, out-channel c = l&3. Self via s==mb.
__global__ __launch_bounds__(256) void k_out(
    const float* __restrict__ p, const int* __restrict__ cnt,
    const int* __restrict__ bucket, const int* __restrict__ ovf_cnt,
    const int2* __restrict__ ovf_list,
    const float* __restrict__ b2, float* __restrict__ out, int n) {
    int node = blockIdx.x * 4 + (threadIdx.x >> 6);
    if (node >= n) return;
    int l = threadIdx.x & 63;
    int s = l >> 2, c = l & 3;
    int m = cnt[node];
    int mb = m < 15 ? m : 15;

    int bkt = bucket[(size_t)node * 16 + s];
    int id = (s < mb) ? bkt : node;
    float acc = (s <= mb) ? p[(size_t)id * 4 + c] : 0.f;
    if (m > 15) {                                           // wave-uniform, rare
        int L = ovf_cnt[0];
        for (int j = s; j < L; j += 16) {
            int2 sd = ovf_list[j];
            if (sd.y == node) acc += p[(size_t)sd.x * 4 + c];
        }
    }
    acc += __shfl_xor(acc, 4, 64);
    acc += __shfl_xor(acc, 8, 64);
    acc += __shfl_xor(acc, 16, 64);
    acc += __shfl_xor(acc, 32, 64);
    if (l < 4)
        out[(size_t)node * 4 + l] =
            fmaxf(fmaf(acc, __builtin_amdgcn_rcpf((float)(m + 1)), b2[l]), 0.f);
}

static inline size_t align4i(size_t v) { return (v + 3) & ~(size_t)3; }

extern "C" void kernel_launch(void* const* d_in, const int* in_sizes, int n_in,
                              void* d_out, int out_size, void* d_ws, size_t ws_size,
                              hipStream_t stream) {
    const float* x  = (const float*)d_in[0];
    const int*   ei = (const int*)d_in[1];
    const float* W1 = (const float*)d_in[2];
    const float* b1 = (const float*)d_in[5];
    const float* W2 = (const float*)d_in[6];
    const float* b2 = (const float*)d_in[9];

    int n = in_sizes[0] / 32;
    int E = in_sizes[1] / 2;
    const int* src = ei;
    const int* dst = ei + E;

    // workspace layout (int units, 16B-aligned sections)
    int* wsi = (int*)d_ws;
    size_t off = 0;
    int* cnt      = wsi + off; off += n;                  // n
    int* ovf_cnt  = wsi + off; off += 1;                  // zeroed with cnt
    size_t off_ovf = align4i(off);
    int2* ovf_list = (int2*)(wsi + off_ovf); off = off_ovf + 2 * (size_t)E;
    size_t off_b  = align4i(off);
    int* bucket   = wsi + off_b;  off = off_b + (size_t)n * 16;
    size_t off_xs = align4i(off);
    float* xs     = (float*)(wsi + off_xs); off = off_xs + (size_t)n * 32;
    float* invd   = (float*)(wsi + off);    off += n;
    size_t off_p  = align4i(off);
    float* p      = (float*)(wsi + off_p);  off = off_p + (size_t)n * 4;
    size_t off_ph = align4i(off);
    ushort* packHi = (ushort*)(wsi + off_ph); off = off_ph + 12800 / 2;
    ushort* packLo = (ushort*)(wsi + off);
    float* out    = (float*)d_out;

    int zb = (n + 1 + TPB - 1) / TPB;
    k_prep<<<zb + 7, TPB, 0, stream>>>(cnt, n + 1, zb, W1, packHi, packLo);
    k_fill<<<(E + TPB - 1) / TPB, TPB, 0, stream>>>(src, dst, cnt, bucket,
                                                    ovf_cnt, ovf_list, E);
    int gblocks = 2 * ((n + 3) / 4);
    k_gather<<<gblocks, TPB, 0, stream>>>(x, cnt, bucket, ovf_cnt, ovf_list,
                                          xs, invd, n);
    k_dense<<<DGRID, TPB, 0, stream>>>(xs, invd, packHi, packLo, b1, W2, p, n);
    k_out<<<(n + 3) / 4, TPB, 0, stream>>>(p, cnt, bucket, ovf_cnt, ovf_list,
                                           b2, out, n);
}